// Round 13
// baseline (219.594 us; speedup 1.0000x reference)
//
#include <hip/hip_runtime.h>
#include <hip/hip_cooperative_groups.h>

namespace cg = cooperative_groups;

constexpr int NN = 10000;
constexpr int NE = 160000;
constexpr int D  = 512;
constexpr int KC = 8;      // wcomb split-K chunks (K=512 -> 8 x 64)
constexpr int MAXDEG = 96; // ELL width; mean deg 16

typedef __attribute__((ext_vector_type(8))) short short8;   // 8 bf16 (4 VGPRs)
typedef __attribute__((ext_vector_type(4))) float f32x4;    // MFMA C/D

static __device__ __forceinline__ ushort f2bf(float f) {
    union { float f; unsigned u; } v; v.f = f;
    unsigned r = (v.u + 0x7FFFu + ((v.u >> 16) & 1u)) >> 16;   // RNE
    return (ushort)r;
}

typedef __attribute__((address_space(3))) unsigned int lds_uint;
typedef const __attribute__((address_space(1))) unsigned int glb_uint;
static __device__ __forceinline__ void gload16(const ushort* g, ushort* l) {
    __builtin_amdgcn_global_load_lds((glb_uint*)g, (lds_uint*)l, 16, 0, 0);
}

// ---------------------------------------------------------------------------
// prep1: blocks [0,1344) wcomb split-K partials | [1344,1600) W2 transpose |
//        [1600,1640) zero deg.
// ---------------------------------------------------------------------------
__global__ __launch_bounds__(256)
void prep1_kernel(const float* __restrict__ We, const float* __restrict__ be,
                  const float* __restrict__ W1, const float* __restrict__ W2,
                  float* __restrict__ part, ushort* __restrict__ W2t,
                  int* __restrict__ deg) {
    __shared__ float tile[32][33];
    const int b   = blockIdx.x;
    const int tid = threadIdx.x;

    if (b < 1344) {
        const int c  = (b & 7) * 64 + (tid & 63);
        const int r  = ((b >> 3) % 21) * 4 + (tid >> 6);
        const int kc = b / 168;
        if (r > 80) return;
        const float* arow = (r < 80) ? (We + (size_t)r * D) : be;
        const int k0 = kc * 64;
        float s = 0.f;
        #pragma unroll
        for (int k = 0; k < 64; k += 4) {
            float4 a = *reinterpret_cast<const float4*>(&arow[k0 + k]);
            s += a.x * W1[(size_t)(k0 + k    ) * D + c];
            s += a.y * W1[(size_t)(k0 + k + 1) * D + c];
            s += a.z * W1[(size_t)(k0 + k + 2) * D + c];
            s += a.w * W1[(size_t)(k0 + k + 3) * D + c];
        }
        part[((size_t)kc * 81 + r) * D + c] = s;
    } else if (b < 1600) {
        const int t  = b - 1344;
        const int bx = (t & 15) * 32;
        const int by = (t >> 4) * 32;
        const int tx = tid & 31;
        const int ty = tid >> 5;
        #pragma unroll
        for (int i = 0; i < 4; ++i)
            tile[ty + 8 * i][tx] = W2[(size_t)(by + ty + 8 * i) * D + bx + tx];
        __syncthreads();
        #pragma unroll
        for (int i = 0; i < 4; ++i)
            W2t[(size_t)(bx + ty + 8 * i) * D + by + tx] = f2bf(tile[tx][ty + 8 * i]);
    } else {
        const int i = (b - 1600) * 256 + tid;
        if (i < NN) deg[i] = 0;
    }
}

// ---------------------------------------------------------------------------
// prep2: blocks [0,256) wcomb_reduce -> WcT | [256,881) fill_ell
// ---------------------------------------------------------------------------
__global__ __launch_bounds__(256)
void prep2_kernel(const float* __restrict__ part, const int* __restrict__ row,
                  ushort* __restrict__ WcT, int* __restrict__ deg,
                  int* __restrict__ ell) {
    const int b   = blockIdx.x;
    const int tid = threadIdx.x;
    if (b < 256) {
        const int i = b * 256 + tid;
        const int k = i >> 9;
        const int c = i & 511;
        float s = 0.f;
        if (k <= 80) {
            #pragma unroll
            for (int kc = 0; kc < KC; ++kc)
                s += part[((size_t)kc * 81 + k) * D + c];
        }
        WcT[(size_t)c * 128 + k] = f2bf(s);
    } else {
        const int e = (b - 256) * 256 + tid;
        if (e < NE) {
            int r = row[e];
            int slot = atomicAdd(&deg[r], 1);
            if (slot < MAXDEG) ell[r * MAXDEG + slot] = e;
        }
    }
}

// ============ gather body (shared by fused + fallback) ============
static __device__ __forceinline__ void gather_body(
        int n, int lane,
        const int* __restrict__ deg, const int* __restrict__ ell,
        const float* __restrict__ rbf, const float* __restrict__ ang,
        ushort* __restrict__ aggX) {
    int d = deg[n];
    if (d > MAXDEG) d = MAXDEG;
    const int* en = ell + (size_t)n * MAXDEG;
    float s1 = 0.f, s2 = 0.f;
    int i = 0;
    for (; i + 8 <= d; i += 8) {
        int e[8];
        #pragma unroll
        for (int j = 0; j < 8; ++j) e[j] = en[i + j];
        float v[8];
        #pragma unroll
        for (int j = 0; j < 8; ++j) v[j] = rbf[e[j] * 64 + lane];
        if (lane < 16) {
            #pragma unroll
            for (int j = 0; j < 8; ++j) s2 += ang[e[j] * 16 + lane];
        }
        #pragma unroll
        for (int j = 0; j < 8; ++j) s1 += v[j];
    }
    for (; i + 4 <= d; i += 4) {
        const int e0 = en[i], e1 = en[i + 1], e2 = en[i + 2], e3 = en[i + 3];
        const float v0 = rbf[e0 * 64 + lane];
        const float v1 = rbf[e1 * 64 + lane];
        const float v2 = rbf[e2 * 64 + lane];
        const float v3 = rbf[e3 * 64 + lane];
        if (lane < 16) {
            s2 += ang[e0 * 16 + lane] + ang[e1 * 16 + lane]
                + ang[e2 * 16 + lane] + ang[e3 * 16 + lane];
        }
        s1 += v0 + v1 + v2 + v3;
    }
    for (; i < d; ++i) {
        const int e = en[i];
        s1 += rbf[e * 64 + lane];
        if (lane < 16) s2 += ang[e * 16 + lane];
    }
    aggX[(size_t)n * 128 + lane] = f2bf(s1);
    const float v2 = (lane < 16) ? s2 : (lane == 16 ? (float)d : 0.f);
    aggX[(size_t)n * 128 + 64 + lane] = f2bf(v2);
}

// ---------------------------------------------------------------------------
// fused cooperative kernel. R13 fix for R12's silent launch failure:
// __launch_bounds__(256,3) caps VGPR so occupancy = 3 blocks/CU (LDS 48KB
// <= 53.3KB) -> coop capacity 768 >= grid 632. Fallback path in host code.
// ---------------------------------------------------------------------------
__global__ __launch_bounds__(256, 3)
void fused_kernel(const int* __restrict__ deg, const int* __restrict__ ell,
                  const float* __restrict__ rbf, const float* __restrict__ ang,
                  ushort* __restrict__ aggX, const ushort* __restrict__ WcT,
                  const float* __restrict__ b1, ushort* __restrict__ h1,
                  const ushort* __restrict__ W2t, const float* __restrict__ b2,
                  const float* __restrict__ x, float* __restrict__ out) {
    __shared__ ushort smem[24576];   // 48 KB, unioned across phases
    cg::grid_group grid = cg::this_grid();

    const int tid  = threadIdx.x;
    const int lane = tid & 63;
    const int wid  = tid >> 6;

    // ---------------- phase 1: gather (grid-stride) ----------------
    for (int g = blockIdx.x; g < NN / 4; g += gridDim.x)
        gather_body(g * 4 + wid, lane, deg, ell, rbf, ang, aggX);
    grid.sync();

    // block -> tile mapping (XCD-bijective, shared by phases 2/3)
    const int l = blockIdx.x;
    const int cpx = gridDim.x >> 3;             // 79
    const int t_ = (l & 7) * cpx + (l >> 3);
    const int n0 = (t_ & 7) * 64;
    const int m0 = (t_ >> 3) * 128;
    constexpr int M = NN;

    // ---------------- phase 2: h1 MFMA (single K-tile 128) ----------------
    {
        ushort* As = smem;            // 128*128
        ushort* Bs = smem + 16384;    //  64*128
        const int rg = lane >> 4;
        const int ch = lane & 15;

        f32x4 acc[2][4] = {};

        #pragma unroll
        for (int j = 0; j < 8; ++j) {
            const int r  = wid * 32 + j * 4 + rg;
            const int gm = (m0 + r < M) ? (m0 + r) : (M - 1);
            const int cs = (ch ^ (r & 7)) * 8;
            const int rowbase = wid * 32 + j * 4;
            gload16(aggX + (size_t)gm * 128 + cs, &As[rowbase * 128]);
        }
        #pragma unroll
        for (int j = 0; j < 4; ++j) {
            const int r  = wid * 16 + j * 4 + rg;
            const int cs = (ch ^ (r & 7)) * 8;
            const int rowbase = wid * 16 + j * 4;
            gload16(WcT + (size_t)(n0 + r) * 128 + cs, &Bs[rowbase * 128]);
        }
        __syncthreads();

        #pragma unroll
        for (int kk = 0; kk < 4; ++kk) {
            const int kc = kk * 4 + (lane >> 4);
            short8 af[2], bfr[4];
            #pragma unroll
            for (int mf = 0; mf < 2; ++mf) {
                const int ar = wid * 32 + mf * 16 + (lane & 15);
                af[mf] = *reinterpret_cast<const short8*>(
                    &As[ar * 128 + ((kc ^ (ar & 7)) * 8)]);
            }
            #pragma unroll
            for (int nf = 0; nf < 4; ++nf) {
                const int br = nf * 16 + (lane & 15);
                bfr[nf] = *reinterpret_cast<const short8*>(
                    &Bs[br * 128 + ((kc ^ (br & 7)) * 8)]);
            }
            #pragma unroll
            for (int mf = 0; mf < 2; ++mf)
                #pragma unroll
                for (int nf = 0; nf < 4; ++nf)
                    acc[mf][nf] = __builtin_amdgcn_mfma_f32_16x16x32_bf16(
                        af[mf], bfr[nf], acc[mf][nf], 0, 0, 0);
        }

        #pragma unroll
        for (int mf = 0; mf < 2; ++mf) {
            const int rowb = m0 + wid * 32 + mf * 16 + ((lane >> 4) << 2);
            #pragma unroll
            for (int nf = 0; nf < 4; ++nf) {
                const int col = n0 + nf * 16 + (lane & 15);
                const float bv = b1[col];
                #pragma unroll
                for (int r = 0; r < 4; ++r) {
                    const int row = rowb + r;
                    if (row < M)
                        h1[(size_t)row * D + col] =
                            f2bf(fmaxf(acc[mf][nf][r] + bv, 0.f));
                }
            }
        }
    }
    __syncthreads();
    grid.sync();

    // ---------------- phase 3: out MFMA (BK=64, 2-phase dbuf) ----------------
    {
        ushort* As0 = smem;                 // [2][128*64]
        ushort* Bs0 = smem + 16384;         // [2][64*64]
        const int sr = lane >> 3;
        const int sc = lane & 7;

        f32x4 acc[2][4] = {};
        constexpr int KTILES = D / 64;

        auto stage = [&](int buf, int t) {
            #pragma unroll
            for (int j = 0; j < 4; ++j) {
                const int r  = wid * 32 + j * 8 + sr;
                const int gm = (m0 + r < M) ? (m0 + r) : (M - 1);
                const int cs = (sc ^ (r & 7)) * 8;
                const int rowbase = wid * 32 + j * 8;
                gload16(h1 + (size_t)gm * D + t * 64 + cs,
                        &As0[buf * 8192 + rowbase * 64]);
            }
            #pragma unroll
            for (int j = 0; j < 2; ++j) {
                const int r  = wid * 16 + j * 8 + sr;
                const int cs = (sc ^ (r & 7)) * 8;
                const int rowbase = wid * 16 + j * 8;
                gload16(W2t + (size_t)(n0 + r) * D + t * 64 + cs,
                        &Bs0[buf * 4096 + rowbase * 64]);
            }
        };

        stage(0, 0);
        __syncthreads();

        for (int t = 0; t < KTILES; ++t) {
            const int cur = t & 1;
            if (t + 1 < KTILES) stage(cur ^ 1, t + 1);
            #pragma unroll
            for (int kk = 0; kk < 2; ++kk) {
                const int kc = kk * 4 + (lane >> 4);
                short8 af[2], bfr[4];
                #pragma unroll
                for (int mf = 0; mf < 2; ++mf) {
                    const int ar = wid * 32 + mf * 16 + (lane & 15);
                    af[mf] = *reinterpret_cast<const short8*>(
                        &As0[cur * 8192 + ar * 64 + ((kc ^ (ar & 7)) * 8)]);
                }
                #pragma unroll
                for (int nf = 0; nf < 4; ++nf) {
                    const int br = nf * 16 + (lane & 15);
                    bfr[nf] = *reinterpret_cast<const short8*>(
                        &Bs0[cur * 4096 + br * 64 + ((kc ^ (br & 7)) * 8)]);
                }
                #pragma unroll
                for (int mf = 0; mf < 2; ++mf)
                    #pragma unroll
                    for (int nf = 0; nf < 4; ++nf)
                        acc[mf][nf] = __builtin_amdgcn_mfma_f32_16x16x32_bf16(
                            af[mf], bfr[nf], acc[mf][nf], 0, 0, 0);
            }
            __syncthreads();
        }

        #pragma unroll
        for (int mf = 0; mf < 2; ++mf) {
            const int rowb = m0 + wid * 32 + mf * 16 + ((lane >> 4) << 2);
            #pragma unroll
            for (int nf = 0; nf < 4; ++nf) {
                const int col = n0 + nf * 16 + (lane & 15);
                const float bv = b2[col];
                #pragma unroll
                for (int r = 0; r < 4; ++r) {
                    const int row = rowb + r;
                    if (row < M)
                        out[(size_t)row * D + col] =
                            acc[mf][nf][r] + bv + x[(size_t)row * D + col];
                }
            }
        }
    }
}

// ============ standalone fallbacks (verified R11 bodies) ============
__global__ __launch_bounds__(256)
void gather_agg_kernel(const int* __restrict__ deg, const int* __restrict__ ell,
                       const float* __restrict__ rbf, const float* __restrict__ ang,
                       ushort* __restrict__ aggX) {
    const int n = blockIdx.x * 4 + (threadIdx.x >> 6);
    if (n < NN) gather_body(n, threadIdx.x & 63, deg, ell, rbf, ang, aggX);
}

__global__ __launch_bounds__(256)
void h1_mfma_kernel(const ushort* __restrict__ A, const ushort* __restrict__ Bt,
                    const float* __restrict__ b1, ushort* __restrict__ H, int M) {
    __shared__ ushort As[128 * 128];
    __shared__ ushort Bs[64 * 128];
    const int tid  = threadIdx.x;
    const int lane = tid & 63;
    const int wid  = tid >> 6;

    const int l = blockIdx.y * gridDim.x + blockIdx.x;
    const int cpx = (gridDim.x * gridDim.y) >> 3;
    const int t_ = (l & 7) * cpx + (l >> 3);
    const int n0 = (t_ & 7) * 64;
    const int m0 = (t_ >> 3) * 128;

    const int rg = lane >> 4;
    const int ch = lane & 15;

    f32x4 acc[2][4] = {};

    #pragma unroll
    for (int j = 0; j < 8; ++j) {
        const int r  = wid * 32 + j * 4 + rg;
        const int gm = (m0 + r < M) ? (m0 + r) : (M - 1);
        const int cs = (ch ^ (r & 7)) * 8;
        const int rowbase = wid * 32 + j * 4;
        gload16(A + (size_t)gm * 128 + cs, &As[rowbase * 128]);
    }
    #pragma unroll
    for (int j = 0; j < 4; ++j) {
        const int r  = wid * 16 + j * 4 + rg;
        const int cs = (ch ^ (r & 7)) * 8;
        const int rowbase = wid * 16 + j * 4;
        gload16(Bt + (size_t)(n0 + r) * 128 + cs, &Bs[rowbase * 128]);
    }
    __syncthreads();

    #pragma unroll
    for (int kk = 0; kk < 4; ++kk) {
        const int kc = kk * 4 + (lane >> 4);
        short8 af[2], bfr[4];
        #pragma unroll
        for (int mf = 0; mf < 2; ++mf) {
            const int ar = wid * 32 + mf * 16 + (lane & 15);
            af[mf] = *reinterpret_cast<const short8*>(
                &As[ar * 128 + ((kc ^ (ar & 7)) * 8)]);
        }
        #pragma unroll
        for (int nf = 0; nf < 4; ++nf) {
            const int br = nf * 16 + (lane & 15);
            bfr[nf] = *reinterpret_cast<const short8*>(
                &Bs[br * 128 + ((kc ^ (br & 7)) * 8)]);
        }
        #pragma unroll
        for (int mf = 0; mf < 2; ++mf)
            #pragma unroll
            for (int nf = 0; nf < 4; ++nf)
                acc[mf][nf] = __builtin_amdgcn_mfma_f32_16x16x32_bf16(
                    af[mf], bfr[nf], acc[mf][nf], 0, 0, 0);
    }

    #pragma unroll
    for (int mf = 0; mf < 2; ++mf) {
        const int rowb = m0 + wid * 32 + mf * 16 + ((lane >> 4) << 2);
        #pragma unroll
        for (int nf = 0; nf < 4; ++nf) {
            const int col = n0 + nf * 16 + (lane & 15);
            const float bv = b1[col];
            #pragma unroll
            for (int r = 0; r < 4; ++r) {
                const int row = rowb + r;
                if (row < M)
                    H[(size_t)row * D + col] = f2bf(fmaxf(acc[mf][nf][r] + bv, 0.f));
            }
        }
    }
}

__global__ __launch_bounds__(256)
void mfma_gemm_kernel(const ushort* __restrict__ A, const ushort* __restrict__ Bt,
                      const float* __restrict__ bias, const float* __restrict__ xres,
                      float* __restrict__ Cout, int M) {
    __shared__ ushort As[2][128 * 64];
    __shared__ ushort Bs[2][64 * 64];
    const int tid  = threadIdx.x;
    const int lane = tid & 63;
    const int wid  = tid >> 6;

    const int l = blockIdx.y * gridDim.x + blockIdx.x;
    const int cpx = (gridDim.x * gridDim.y) >> 3;
    const int t_ = (l & 7) * cpx + (l >> 3);
    const int n0 = (t_ & 7) * 64;
    const int m0 = (t_ >> 3) * 128;

    const int sr = lane >> 3;
    const int sc = lane & 7;

    f32x4 acc[2][4] = {};
    constexpr int KTILES = D / 64;

    auto stage = [&](int buf, int t) {
        #pragma unroll
        for (int j = 0; j < 4; ++j) {
            const int r  = wid * 32 + j * 8 + sr;
            const int gm = (m0 + r < M) ? (m0 + r) : (M - 1);
            const int cs = (sc ^ (r & 7)) * 8;
            const int rowbase = wid * 32 + j * 8;
            gload16(A + (size_t)gm * D + t * 64 + cs, &As[buf][rowbase * 64]);
        }
        #pragma unroll
        for (int j = 0; j < 2; ++j) {
            const int r  = wid * 16 + j * 8 + sr;
            const int cs = (sc ^ (r & 7)) * 8;
            const int rowbase = wid * 16 + j * 8;
            gload16(Bt + (size_t)(n0 + r) * D + t * 64 + cs, &Bs[buf][rowbase * 64]);
        }
    };

    stage(0, 0);
    __syncthreads();

    for (int t = 0; t < KTILES; ++t) {
        const int cur = t & 1;
        if (t + 1 < KTILES) stage(cur ^ 1, t + 1);
        #pragma unroll
        for (int kk = 0; kk < 2; ++kk) {
            const int kc = kk * 4 + (lane >> 4);
            short8 af[2], bfr[4];
            #pragma unroll
            for (int mf = 0; mf < 2; ++mf) {
                const int ar = wid * 32 + mf * 16 + (lane & 15);
                af[mf] = *reinterpret_cast<const short8*>(
                    &As[cur][ar * 64 + ((kc ^ (ar & 7)) * 8)]);
            }
            #pragma unroll
            for (int nf = 0; nf < 4; ++nf) {
                const int br = nf * 16 + (lane & 15);
                bfr[nf] = *reinterpret_cast<const short8*>(
                    &Bs[cur][br * 64 + ((kc ^ (br & 7)) * 8)]);
            }
            #pragma unroll
            for (int mf = 0; mf < 2; ++mf)
                #pragma unroll
                for (int nf = 0; nf < 4; ++nf)
                    acc[mf][nf] = __builtin_amdgcn_mfma_f32_16x16x32_bf16(
                        af[mf], bfr[nf], acc[mf][nf], 0, 0, 0);
        }
        __syncthreads();
    }

    #pragma unroll
    for (int mf = 0; mf < 2; ++mf) {
        const int rowb = m0 + wid * 32 + mf * 16 + ((lane >> 4) << 2);
        #pragma unroll
        for (int nf = 0; nf < 4; ++nf) {
            const int col = n0 + nf * 16 + (lane & 15);
            const float bv = bias[col];
            #pragma unroll
            for (int r = 0; r < 4; ++r) {
                const int row = rowb + r;
                if (row < M)
                    Cout[(size_t)row * D + col] =
                        acc[mf][nf][r] + bv + xres[(size_t)row * D + col];
            }
        }
    }
}

extern "C" void kernel_launch(void* const* d_in, const int* in_sizes, int n_in,
                              void* d_out, int out_size, void* d_ws, size_t ws_size,
                              hipStream_t stream) {
    const float* x      = (const float*)d_in[0];
    const int*   edge_index = (const int*)d_in[2];
    const float* rbf    = (const float*)d_in[3];
    const float* ang    = (const float*)d_in[4];
    const float* W_edge = (const float*)d_in[5];
    const float* b_edge = (const float*)d_in[6];
    const float* W1     = (const float*)d_in[7];
    const float* b1     = (const float*)d_in[8];
    const float* W2     = (const float*)d_in[9];
    const float* b2     = (const float*)d_in[10];
    float* out = (float*)d_out;

    char* w = (char*)d_ws;
    ushort* aggX = (ushort*)w;                       //  2,560,000 B [NN][128]
    ushort* W2t  = (ushort*)(w + 2560000);           //    524,288 B
    ushort* WcT  = (ushort*)(w + 3084288);           //    131,072 B [512][128]
    int*    deg  = (int*)(w + 3215360);              //     40,000 B
    float*  part = (float*)(w + 3255360);            //  1,327,104 B
    int*    ell  = (int*)(w + 4582464);              //  3,840,000 B
    ushort* h1   = (ushort*)(w + 3255360);           // 10,240,000 B (aliases part+ell)

    prep1_kernel<<<1640, 256, 0, stream>>>(W_edge, b_edge, W1, W2, part, W2t, deg);
    prep2_kernel<<<881, 256, 0, stream>>>(part, edge_index, WcT, deg, ell);

    const int* degc = deg;
    const int* ellc = ell;
    const ushort* WcTc = WcT;
    const ushort* W2tc = W2t;
    void* args[] = {(void*)&degc, (void*)&ellc, (void*)&rbf, (void*)&ang,
                    (void*)&aggX, (void*)&WcTc, (void*)&b1, (void*)&h1,
                    (void*)&W2tc, (void*)&b2, (void*)&x, (void*)&out};
    hipError_t err = hipLaunchCooperativeKernel((void*)fused_kernel, dim3(632),
                                                dim3(256), args, 0, stream);
    if (err != hipSuccess) {
        // fallback: verified R11 3-kernel path (identical math)
        gather_agg_kernel<<<NN / 4, 256, 0, stream>>>(deg, ell, rbf, ang, aggX);
        dim3 ggrid(D / 64, (NN + 127) / 128);   // 8 x 79 = 632
        h1_mfma_kernel<<<ggrid, 256, 0, stream>>>(aggX, WcT, b1, h1, NN);
        mfma_gemm_kernel<<<ggrid, 256, 0, stream>>>(h1, W2t, b2, x, out, NN);
    }
}

// Round 14
// 96.504 us; speedup vs baseline: 2.2755x; 2.2755x over previous
//
#include <hip/hip_runtime.h>

constexpr int NN = 10000;
constexpr int NE = 160000;
constexpr int D  = 512;
constexpr int KC = 8;      // wcomb split-K chunks (K=512 -> 8 x 64)
constexpr int MAXDEG = 96; // ELL width; mean deg 16

typedef __attribute__((ext_vector_type(8))) short short8;   // 8 bf16 (4 VGPRs)
typedef __attribute__((ext_vector_type(4))) float f32x4;    // MFMA C/D

static __device__ __forceinline__ ushort f2bf(float f) {
    union { float f; unsigned u; } v; v.f = f;
    unsigned r = (v.u + 0x7FFFu + ((v.u >> 16) & 1u)) >> 16;   // RNE
    return (ushort)r;
}

typedef __attribute__((address_space(3))) unsigned int lds_uint;
typedef const __attribute__((address_space(1))) unsigned int glb_uint;
static __device__ __forceinline__ void gload16(const ushort* g, ushort* l) {
    __builtin_amdgcn_global_load_lds((glb_uint*)g, (lds_uint*)l, 16, 0, 0);
}

// ---------------------------------------------------------------------------
// prep1: blocks [0,1344) wcomb split-K partials | [1344,1600) W2 transpose |
//        [1600,1640) zero deg.  (verified R10)
// ---------------------------------------------------------------------------
__global__ __launch_bounds__(256)
void prep1_kernel(const float* __restrict__ We, const float* __restrict__ be,
                  const float* __restrict__ W1, const float* __restrict__ W2,
                  float* __restrict__ part, ushort* __restrict__ W2t,
                  int* __restrict__ deg) {
    __shared__ float tile[32][33];
    const int b   = blockIdx.x;
    const int tid = threadIdx.x;

    if (b < 1344) {
        const int c  = (b & 7) * 64 + (tid & 63);
        const int r  = ((b >> 3) % 21) * 4 + (tid >> 6);
        const int kc = b / 168;
        if (r > 80) return;
        const float* arow = (r < 80) ? (We + (size_t)r * D) : be;
        const int k0 = kc * 64;
        float s = 0.f;
        #pragma unroll
        for (int k = 0; k < 64; k += 4) {
            float4 a = *reinterpret_cast<const float4*>(&arow[k0 + k]);
            s += a.x * W1[(size_t)(k0 + k    ) * D + c];
            s += a.y * W1[(size_t)(k0 + k + 1) * D + c];
            s += a.z * W1[(size_t)(k0 + k + 2) * D + c];
            s += a.w * W1[(size_t)(k0 + k + 3) * D + c];
        }
        part[((size_t)kc * 81 + r) * D + c] = s;
    } else if (b < 1600) {
        const int t  = b - 1344;
        const int bx = (t & 15) * 32;
        const int by = (t >> 4) * 32;
        const int tx = tid & 31;
        const int ty = tid >> 5;
        #pragma unroll
        for (int i = 0; i < 4; ++i)
            tile[ty + 8 * i][tx] = W2[(size_t)(by + ty + 8 * i) * D + bx + tx];
        __syncthreads();
        #pragma unroll
        for (int i = 0; i < 4; ++i)
            W2t[(size_t)(bx + ty + 8 * i) * D + by + tx] = f2bf(tile[tx][ty + 8 * i]);
    } else {
        const int i = (b - 1600) * 256 + tid;
        if (i < NN) deg[i] = 0;
    }
}

// ---------------------------------------------------------------------------
// prep2: blocks [0,256) wcomb_reduce -> WcT | [256,881) fill_ell  (verified)
// ---------------------------------------------------------------------------
__global__ __launch_bounds__(256)
void prep2_kernel(const float* __restrict__ part, const int* __restrict__ row,
                  ushort* __restrict__ WcT, int* __restrict__ deg,
                  int* __restrict__ ell) {
    const int b   = blockIdx.x;
    const int tid = threadIdx.x;
    if (b < 256) {
        const int i = b * 256 + tid;
        const int k = i >> 9;
        const int c = i & 511;
        float s = 0.f;
        if (k <= 80) {
            #pragma unroll
            for (int kc = 0; kc < KC; ++kc)
                s += part[((size_t)kc * 81 + k) * D + c];
        }
        WcT[(size_t)c * 128 + k] = f2bf(s);
    } else {
        const int e = (b - 256) * 256 + tid;
        if (e < NE) {
            int r = row[e];
            int slot = atomicAdd(&deg[r], 1);
            if (slot < MAXDEG) ell[r * MAXDEG + slot] = e;
        }
    }
}

// ---------------------------------------------------------------------------
// gather: one wave per node -> bf16 aggX[n][128]  (verified R11)
//   cols 0..63 rbf sums, 64..79 ang sums, 80 = cnt, 81..127 = 0
// ---------------------------------------------------------------------------
__global__ __launch_bounds__(256)
void gather_agg_kernel(const int* __restrict__ deg, const int* __restrict__ ell,
                       const float* __restrict__ rbf, const float* __restrict__ ang,
                       ushort* __restrict__ aggX) {
    const int wv   = threadIdx.x >> 6;
    const int lane = threadIdx.x & 63;
    const int n    = blockIdx.x * 4 + wv;
    if (n >= NN) return;
    int d = deg[n];
    if (d > MAXDEG) d = MAXDEG;
    const int* en = ell + (size_t)n * MAXDEG;
    float s1 = 0.f, s2 = 0.f;
    int i = 0;
    for (; i + 8 <= d; i += 8) {
        int e[8];
        #pragma unroll
        for (int j = 0; j < 8; ++j) e[j] = en[i + j];
        float v[8];
        #pragma unroll
        for (int j = 0; j < 8; ++j) v[j] = rbf[e[j] * 64 + lane];
        if (lane < 16) {
            #pragma unroll
            for (int j = 0; j < 8; ++j) s2 += ang[e[j] * 16 + lane];
        }
        #pragma unroll
        for (int j = 0; j < 8; ++j) s1 += v[j];
    }
    for (; i + 4 <= d; i += 4) {
        const int e0 = en[i], e1 = en[i + 1], e2 = en[i + 2], e3 = en[i + 3];
        const float v0 = rbf[e0 * 64 + lane];
        const float v1 = rbf[e1 * 64 + lane];
        const float v2 = rbf[e2 * 64 + lane];
        const float v3 = rbf[e3 * 64 + lane];
        if (lane < 16) {
            s2 += ang[e0 * 16 + lane] + ang[e1 * 16 + lane]
                + ang[e2 * 16 + lane] + ang[e3 * 16 + lane];
        }
        s1 += v0 + v1 + v2 + v3;
    }
    for (; i < d; ++i) {
        const int e = en[i];
        s1 += rbf[e * 64 + lane];
        if (lane < 16) s2 += ang[e * 16 + lane];
    }
    aggX[(size_t)n * 128 + lane] = f2bf(s1);
    const float v2 = (lane < 16) ? s2 : (lane == 16 ? (float)d : 0.f);
    aggX[(size_t)n * 128 + 64 + lane] = f2bf(v2);
}

// ---------------------------------------------------------------------------
// tail: out = relu(aggX@WcT^T+b1) @ W2t^T + b2 + x  -- h1 fused by per-block
// recompute (R14). No grid sync: h1 rows needed by out tile (m0,n0) depend
// only on aggX rows m0..m0+128 (block-local). Per k-tile t:
//   1 barrier -> h1-chunk MFMA (A=aggX regs, B=Wc_s LDS) -> relu+bf16 into
//   wave-PRIVATE Ah pane (no barrier; same wave reads its own rows) ->
//   out MFMA (A=Ah, B=W2_s) -> stage t+1 (dbuf).
// LDS 64KB: Wc_s 2x16K + W2_s 2x8K + Ah 16K. MFMA 3x of split path but MFMA
// was ~0.6us total -- staging/barrier bound, so recompute is ~free.
// ---------------------------------------------------------------------------
__global__ __launch_bounds__(256)
void tail_kernel(const ushort* __restrict__ aggX,  // [M][128] bf16
                 const ushort* __restrict__ WcT,   // [512][128] bf16 [n][k]
                 const float* __restrict__ b1,
                 const ushort* __restrict__ W2t,   // [512][512] bf16 [n][k]
                 const float* __restrict__ b2,
                 const float* __restrict__ x,
                 float* __restrict__ out, int M) {
    __shared__ ushort Wc_s[2][64 * 128];   // 32 KB
    __shared__ ushort W2_s[2][64 * 64];    // 16 KB
    __shared__ ushort Ah[128 * 64];        // 16 KB (wave-private panes)
    const int tid  = threadIdx.x;
    const int lane = tid & 63;
    const int wid  = tid >> 6;

    const int l = blockIdx.y * gridDim.x + blockIdx.x;
    const int cpx = (gridDim.x * gridDim.y) >> 3;   // 79
    const int t_ = (l & 7) * cpx + (l >> 3);
    const int n0 = (t_ & 7) * 64;
    const int m0 = (t_ >> 3) * 128;

    // ---- aggX A-fragments in registers (loaded once; same for all t) ----
    short8 afh[2][4];
    #pragma unroll
    for (int mf = 0; mf < 2; ++mf) {
        const int row = m0 + wid * 32 + mf * 16 + (lane & 15);
        const int gm = (row < M) ? row : (M - 1);
        #pragma unroll
        for (int kk = 0; kk < 4; ++kk)
            afh[mf][kk] = *reinterpret_cast<const short8*>(
                &aggX[(size_t)gm * 128 + kk * 32 + ((lane >> 4) << 3)]);
    }

    // staging: Wc chunk t = WcT rows [t*64,+64) x 128k (16 chunks/row);
    //          W2 chunk t = W2t rows [n0,+64) x k [t*64,+64) (8 chunks/row)
    const int rg4 = lane >> 4;        // 0..3 (Wc: 4 rows per gload)
    const int ch16 = lane & 15;       // Wc chunk
    const int rg8 = lane >> 3;        // 0..7 (W2: 8 rows per gload)
    const int ch8 = lane & 7;         // W2 chunk

    auto stageWc = [&](int buf, int t) {
        #pragma unroll
        for (int j = 0; j < 4; ++j) {
            const int r  = wid * 16 + j * 4 + rg4;
            const int cs = (ch16 ^ (r & 7)) * 8;
            const int rowbase = wid * 16 + j * 4;
            gload16(WcT + (size_t)(t * 64 + r) * 128 + cs, &Wc_s[buf][rowbase * 128]);
        }
    };
    auto stageW2 = [&](int buf, int t) {
        #pragma unroll
        for (int j = 0; j < 2; ++j) {
            const int r  = wid * 16 + j * 8 + rg8;
            const int cs = (ch8 ^ (r & 7)) * 8;
            const int rowbase = wid * 16 + j * 8;
            gload16(W2t + (size_t)(n0 + r) * D + t * 64 + cs, &W2_s[buf][rowbase * 64]);
        }
    };

    f32x4 acc[2][4] = {};
    constexpr int KTILES = D / 64;

    stageWc(0, 0);
    stageW2(0, 0);

    for (int t = 0; t < KTILES; ++t) {
        const int cur = t & 1;
        __syncthreads();   // staging(t) visible; prev iter fully done

        // ---- h1 chunk: acch = aggX @ WcT[t*64..+64]^T ----
        f32x4 acch[2][4] = {};
        #pragma unroll
        for (int kk = 0; kk < 4; ++kk) {
            const int kc = kk * 4 + (lane >> 4);
            short8 bfh[4];
            #pragma unroll
            for (int nf = 0; nf < 4; ++nf) {
                const int br = nf * 16 + (lane & 15);
                bfh[nf] = *reinterpret_cast<const short8*>(
                    &Wc_s[cur][br * 128 + ((kc ^ (br & 7)) * 8)]);
            }
            #pragma unroll
            for (int mf = 0; mf < 2; ++mf)
                #pragma unroll
                for (int nf = 0; nf < 4; ++nf)
                    acch[mf][nf] = __builtin_amdgcn_mfma_f32_16x16x32_bf16(
                        afh[mf][kk], bfh[nf], acch[mf][nf], 0, 0, 0);
        }

        // ---- relu + bf16 -> Ah (wave-private rows; swizzled) ----
        #pragma unroll
        for (int mf = 0; mf < 2; ++mf) {
            const int rowb = wid * 32 + mf * 16 + ((lane >> 4) << 2);
            #pragma unroll
            for (int nf = 0; nf < 4; ++nf) {
                const int col = nf * 16 + (lane & 15);
                const float bv = b1[t * 64 + n0 * 0 + col + 0 * D] ;  // b1[t*64+col]
                #pragma unroll
                for (int r = 0; r < 4; ++r) {
                    const int row = rowb + r;
                    const float v = fmaxf(acch[mf][nf][r] + b1[t * 64 + col], 0.f);
                    Ah[(row * 64 + col) ^ ((row & 7) << 3)] = f2bf(v);
                }
                (void)bv;
            }
        }
        // wave-local write->read: compiler inserts lgkmcnt (same LDS object)

        // ---- out step: acc += h1chunk @ W2t[n0..,t*64..]^T ----
        #pragma unroll
        for (int kk = 0; kk < 2; ++kk) {
            const int kc = kk * 4 + (lane >> 4);
            short8 af[2], bfr[4];
            #pragma unroll
            for (int mf = 0; mf < 2; ++mf) {
                const int ar = wid * 32 + mf * 16 + (lane & 15);
                const int koff = kk * 32 + ((lane >> 4) << 3);
                af[mf] = *reinterpret_cast<const short8*>(
                    &Ah[(ar * 64 + koff) ^ ((ar & 7) << 3)]);
            }
            #pragma unroll
            for (int nf = 0; nf < 4; ++nf) {
                const int br = nf * 16 + (lane & 15);
                bfr[nf] = *reinterpret_cast<const short8*>(
                    &W2_s[cur][br * 64 + ((kc ^ (br & 7)) * 8)]);
            }
            #pragma unroll
            for (int mf = 0; mf < 2; ++mf)
                #pragma unroll
                for (int nf = 0; nf < 4; ++nf)
                    acc[mf][nf] = __builtin_amdgcn_mfma_f32_16x16x32_bf16(
                        af[mf], bfr[nf], acc[mf][nf], 0, 0, 0);
        }

        if (t + 1 < KTILES) {
            stageWc(cur ^ 1, t + 1);
            stageW2(cur ^ 1, t + 1);
        }
    }

    // ---- epilogue: + b2 + x ----
    #pragma unroll
    for (int mf = 0; mf < 2; ++mf) {
        const int rowb = m0 + wid * 32 + mf * 16 + ((lane >> 4) << 2);
        #pragma unroll
        for (int nf = 0; nf < 4; ++nf) {
            const int col = n0 + nf * 16 + (lane & 15);
            const float bv = b2[col];
            #pragma unroll
            for (int r = 0; r < 4; ++r) {
                const int row = rowb + r;
                if (row < M)
                    out[(size_t)row * D + col] =
                        acc[mf][nf][r] + bv + x[(size_t)row * D + col];
            }
        }
    }
}

extern "C" void kernel_launch(void* const* d_in, const int* in_sizes, int n_in,
                              void* d_out, int out_size, void* d_ws, size_t ws_size,
                              hipStream_t stream) {
    const float* x      = (const float*)d_in[0];
    const int*   edge_index = (const int*)d_in[2];
    const float* rbf    = (const float*)d_in[3];
    const float* ang    = (const float*)d_in[4];
    const float* W_edge = (const float*)d_in[5];
    const float* b_edge = (const float*)d_in[6];
    const float* W1     = (const float*)d_in[7];
    const float* b1     = (const float*)d_in[8];
    const float* W2     = (const float*)d_in[9];
    const float* b2     = (const float*)d_in[10];
    float* out = (float*)d_out;

    char* w = (char*)d_ws;
    ushort* aggX = (ushort*)w;                       //  2,560,000 B [NN][128]
    ushort* W2t  = (ushort*)(w + 2560000);           //    524,288 B
    ushort* WcT  = (ushort*)(w + 3084288);           //    131,072 B [512][128]
    int*    deg  = (int*)(w + 3215360);              //     40,000 B
    float*  part = (float*)(w + 3255360);            //  1,327,104 B
    int*    ell  = (int*)(w + 4582464);              //  3,840,000 B
    // h1 buffer no longer exists (fused into tail)

    prep1_kernel<<<1640, 256, 0, stream>>>(W_edge, b_edge, W1, W2, part, W2t, deg);
    prep2_kernel<<<881, 256, 0, stream>>>(part, edge_index, WcT, deg, ell);
    gather_agg_kernel<<<NN / 4, 256, 0, stream>>>(deg, ell, rbf, ang, aggX);

    dim3 ggrid(D / 64, (NN + 127) / 128);   // 8 x 79 = 632 blocks, %8==0
    tail_kernel<<<ggrid, 256, 0, stream>>>(aggX, WcT, b1, W2t, b2, x, out, NN);
}

// Round 15
// 67.365 us; speedup vs baseline: 3.2598x; 1.4326x over previous
//
#include <hip/hip_runtime.h>

constexpr int NN = 10000;
constexpr int NE = 160000;
constexpr int D  = 512;
constexpr int KC = 8;      // wcomb split-K chunks (K=512 -> 8 x 64)
constexpr int MAXDEG = 96; // ELL width; mean deg 16

typedef __attribute__((ext_vector_type(8))) short short8;   // 8 bf16 (4 VGPRs)
typedef __attribute__((ext_vector_type(4))) float f32x4;    // MFMA C/D

static __device__ __forceinline__ ushort f2bf(float f) {
    union { float f; unsigned u; } v; v.f = f;
    unsigned r = (v.u + 0x7FFFu + ((v.u >> 16) & 1u)) >> 16;   // RNE
    return (ushort)r;
}

typedef __attribute__((address_space(3))) unsigned int lds_uint;
typedef const __attribute__((address_space(1))) unsigned int glb_uint;
static __device__ __forceinline__ void gload16(const ushort* g, ushort* l) {
    __builtin_amdgcn_global_load_lds((glb_uint*)g, (lds_uint*)l, 16, 0, 0);
}

// ---------------------------------------------------------------------------
// prep1: blocks [0,1344) wcomb split-K partials | [1344,1600) W2 transpose |
//        [1600,1640) zero deg.  (verified R10)
// ---------------------------------------------------------------------------
__global__ __launch_bounds__(256)
void prep1_kernel(const float* __restrict__ We, const float* __restrict__ be,
                  const float* __restrict__ W1, const float* __restrict__ W2,
                  float* __restrict__ part, ushort* __restrict__ W2t,
                  int* __restrict__ deg) {
    __shared__ float tile[32][33];
    const int b   = blockIdx.x;
    const int tid = threadIdx.x;

    if (b < 1344) {
        const int c  = (b & 7) * 64 + (tid & 63);
        const int r  = ((b >> 3) % 21) * 4 + (tid >> 6);
        const int kc = b / 168;
        if (r > 80) return;
        const float* arow = (r < 80) ? (We + (size_t)r * D) : be;
        const int k0 = kc * 64;
        float s = 0.f;
        #pragma unroll
        for (int k = 0; k < 64; k += 4) {
            float4 a = *reinterpret_cast<const float4*>(&arow[k0 + k]);
            s += a.x * W1[(size_t)(k0 + k    ) * D + c];
            s += a.y * W1[(size_t)(k0 + k + 1) * D + c];
            s += a.z * W1[(size_t)(k0 + k + 2) * D + c];
            s += a.w * W1[(size_t)(k0 + k + 3) * D + c];
        }
        part[((size_t)kc * 81 + r) * D + c] = s;
    } else if (b < 1600) {
        const int t  = b - 1344;
        const int bx = (t & 15) * 32;
        const int by = (t >> 4) * 32;
        const int tx = tid & 31;
        const int ty = tid >> 5;
        #pragma unroll
        for (int i = 0; i < 4; ++i)
            tile[ty + 8 * i][tx] = W2[(size_t)(by + ty + 8 * i) * D + bx + tx];
        __syncthreads();
        #pragma unroll
        for (int i = 0; i < 4; ++i)
            W2t[(size_t)(bx + ty + 8 * i) * D + by + tx] = f2bf(tile[tx][ty + 8 * i]);
    } else {
        const int i = (b - 1600) * 256 + tid;
        if (i < NN) deg[i] = 0;
    }
}

// ---------------------------------------------------------------------------
// prep2: blocks [0,256) wcomb_reduce -> WcT | [256,881) fill_ell  (verified)
// ---------------------------------------------------------------------------
__global__ __launch_bounds__(256)
void prep2_kernel(const float* __restrict__ part, const int* __restrict__ row,
                  ushort* __restrict__ WcT, int* __restrict__ deg,
                  int* __restrict__ ell) {
    const int b   = blockIdx.x;
    const int tid = threadIdx.x;
    if (b < 256) {
        const int i = b * 256 + tid;
        const int k = i >> 9;
        const int c = i & 511;
        float s = 0.f;
        if (k <= 80) {
            #pragma unroll
            for (int kc = 0; kc < KC; ++kc)
                s += part[((size_t)kc * 81 + k) * D + c];
        }
        WcT[(size_t)c * 128 + k] = f2bf(s);
    } else {
        const int e = (b - 256) * 256 + tid;
        if (e < NE) {
            int r = row[e];
            int slot = atomicAdd(&deg[r], 1);
            if (slot < MAXDEG) ell[r * MAXDEG + slot] = e;
        }
    }
}

// ---------------------------------------------------------------------------
// gather: one wave per node -> bf16 aggX[n][128]  (verified R11)
//   cols 0..63 rbf sums, 64..79 ang sums, 80 = cnt, 81..127 = 0
// ---------------------------------------------------------------------------
__global__ __launch_bounds__(256)
void gather_agg_kernel(const int* __restrict__ deg, const int* __restrict__ ell,
                       const float* __restrict__ rbf, const float* __restrict__ ang,
                       ushort* __restrict__ aggX) {
    const int wv   = threadIdx.x >> 6;
    const int lane = threadIdx.x & 63;
    const int n    = blockIdx.x * 4 + wv;
    if (n >= NN) return;
    int d = deg[n];
    if (d > MAXDEG) d = MAXDEG;
    const int* en = ell + (size_t)n * MAXDEG;
    float s1 = 0.f, s2 = 0.f;
    int i = 0;
    for (; i + 8 <= d; i += 8) {
        int e[8];
        #pragma unroll
        for (int j = 0; j < 8; ++j) e[j] = en[i + j];
        float v[8];
        #pragma unroll
        for (int j = 0; j < 8; ++j) v[j] = rbf[e[j] * 64 + lane];
        if (lane < 16) {
            #pragma unroll
            for (int j = 0; j < 8; ++j) s2 += ang[e[j] * 16 + lane];
        }
        #pragma unroll
        for (int j = 0; j < 8; ++j) s1 += v[j];
    }
    for (; i + 4 <= d; i += 4) {
        const int e0 = en[i], e1 = en[i + 1], e2 = en[i + 2], e3 = en[i + 3];
        const float v0 = rbf[e0 * 64 + lane];
        const float v1 = rbf[e1 * 64 + lane];
        const float v2 = rbf[e2 * 64 + lane];
        const float v3 = rbf[e3 * 64 + lane];
        if (lane < 16) {
            s2 += ang[e0 * 16 + lane] + ang[e1 * 16 + lane]
                + ang[e2 * 16 + lane] + ang[e3 * 16 + lane];
        }
        s1 += v0 + v1 + v2 + v3;
    }
    for (; i < d; ++i) {
        const int e = en[i];
        s1 += rbf[e * 64 + lane];
        if (lane < 16) s2 += ang[e * 16 + lane];
    }
    aggX[(size_t)n * 128 + lane] = f2bf(s1);
    const float v2 = (lane < 16) ? s2 : (lane == 16 ? (float)d : 0.f);
    aggX[(size_t)n * 128 + 64 + lane] = f2bf(v2);
}

// ---------------------------------------------------------------------------
// h1 MFMA (single K-tile, K=128): h1 = bf16(relu(aggX @ WcT^T + b1))
// 128x64 tile, 4 waves, rule-#21 swizzle.  (verified R11)
// ---------------------------------------------------------------------------
__global__ __launch_bounds__(256)
void h1_mfma_kernel(const ushort* __restrict__ A, const ushort* __restrict__ Bt,
                    const float* __restrict__ b1, ushort* __restrict__ H, int M) {
    __shared__ ushort As[128 * 128];
    __shared__ ushort Bs[64 * 128];
    const int tid  = threadIdx.x;
    const int lane = tid & 63;
    const int wid  = tid >> 6;

    const int l = blockIdx.y * gridDim.x + blockIdx.x;
    const int cpx = (gridDim.x * gridDim.y) >> 3;
    const int t_ = (l & 7) * cpx + (l >> 3);
    const int n0 = (t_ & 7) * 64;
    const int m0 = (t_ >> 3) * 128;

    const int rg = lane >> 4;
    const int ch = lane & 15;

    f32x4 acc[2][4] = {};

    #pragma unroll
    for (int j = 0; j < 8; ++j) {
        const int r  = wid * 32 + j * 4 + rg;
        const int gm = (m0 + r < M) ? (m0 + r) : (M - 1);
        const int cs = (ch ^ (r & 7)) * 8;
        const int rowbase = wid * 32 + j * 4;
        gload16(A + (size_t)gm * 128 + cs, &As[rowbase * 128]);
    }
    #pragma unroll
    for (int j = 0; j < 4; ++j) {
        const int r  = wid * 16 + j * 4 + rg;
        const int cs = (ch ^ (r & 7)) * 8;
        const int rowbase = wid * 16 + j * 4;
        gload16(Bt + (size_t)(n0 + r) * 128 + cs, &Bs[rowbase * 128]);
    }
    __syncthreads();

    #pragma unroll
    for (int kk = 0; kk < 4; ++kk) {
        const int kc = kk * 4 + (lane >> 4);
        short8 af[2], bfr[4];
        #pragma unroll
        for (int mf = 0; mf < 2; ++mf) {
            const int ar = wid * 32 + mf * 16 + (lane & 15);
            af[mf] = *reinterpret_cast<const short8*>(
                &As[ar * 128 + ((kc ^ (ar & 7)) * 8)]);
        }
        #pragma unroll
        for (int nf = 0; nf < 4; ++nf) {
            const int br = nf * 16 + (lane & 15);
            bfr[nf] = *reinterpret_cast<const short8*>(
                &Bs[br * 128 + ((kc ^ (br & 7)) * 8)]);
        }
        #pragma unroll
        for (int mf = 0; mf < 2; ++mf)
            #pragma unroll
            for (int nf = 0; nf < 4; ++nf)
                acc[mf][nf] = __builtin_amdgcn_mfma_f32_16x16x32_bf16(
                    af[mf], bfr[nf], acc[mf][nf], 0, 0, 0);
    }

    #pragma unroll
    for (int mf = 0; mf < 2; ++mf) {
        const int rowb = m0 + wid * 32 + mf * 16 + ((lane >> 4) << 2);
        #pragma unroll
        for (int nf = 0; nf < 4; ++nf) {
            const int col = n0 + nf * 16 + (lane & 15);
            const float bv = b1[col];
            #pragma unroll
            for (int r = 0; r < 4; ++r) {
                const int row = rowb + r;
                if (row < M)
                    H[(size_t)row * D + col] = f2bf(fmaxf(acc[mf][nf][r] + bv, 0.f));
            }
        }
    }
}

// ---------------------------------------------------------------------------
// out MFMA: out = h1 @ W2t^T + b2 + x   (f32 out)
// 128x64 tile, BK=64, 2-phase gload_lds pipeline, rule-#21 swizzle,
// XCD-bijective grid swizzle.  (verified R11)
// R15 addition: x-residual prefetched to registers BEFORE the K-loop --
// its 32 scattered loads were fully latency-exposed after the last barrier.
// ---------------------------------------------------------------------------
__global__ __launch_bounds__(256)
void mfma_gemm_kernel(const ushort* __restrict__ A, const ushort* __restrict__ Bt,
                      const float* __restrict__ bias, const float* __restrict__ xres,
                      float* __restrict__ Cout, int M) {
    __shared__ ushort As[2][128 * 64];
    __shared__ ushort Bs[2][64 * 64];
    const int tid  = threadIdx.x;
    const int lane = tid & 63;
    const int wid  = tid >> 6;

    const int l = blockIdx.y * gridDim.x + blockIdx.x;
    const int cpx = (gridDim.x * gridDim.y) >> 3;
    const int t_ = (l & 7) * cpx + (l >> 3);
    const int n0 = (t_ & 7) * 64;
    const int m0 = (t_ >> 3) * 128;

    const int sr = lane >> 3;
    const int sc = lane & 7;

    f32x4 acc[2][4] = {};
    constexpr int KTILES = D / 64;

    auto stage = [&](int buf, int t) {
        #pragma unroll
        for (int j = 0; j < 4; ++j) {
            const int r  = wid * 32 + j * 8 + sr;
            const int gm = (m0 + r < M) ? (m0 + r) : (M - 1);
            const int cs = (sc ^ (r & 7)) * 8;
            const int rowbase = wid * 32 + j * 8;
            gload16(A + (size_t)gm * D + t * 64 + cs, &As[buf][rowbase * 64]);
        }
        #pragma unroll
        for (int j = 0; j < 2; ++j) {
            const int r  = wid * 16 + j * 8 + sr;
            const int cs = (sc ^ (r & 7)) * 8;
            const int rowbase = wid * 16 + j * 8;
            gload16(Bt + (size_t)(n0 + r) * D + t * 64 + cs, &Bs[buf][rowbase * 64]);
        }
    };

    stage(0, 0);

    // prefetch x residual (independent of K-loop; hides under it)
    float xv[2][4][4];
    #pragma unroll
    for (int mf = 0; mf < 2; ++mf) {
        const int rowb = m0 + wid * 32 + mf * 16 + ((lane >> 4) << 2);
        #pragma unroll
        for (int nf = 0; nf < 4; ++nf) {
            const int col = n0 + nf * 16 + (lane & 15);
            #pragma unroll
            for (int r = 0; r < 4; ++r) {
                const int row = (rowb + r < M) ? (rowb + r) : (M - 1);
                xv[mf][nf][r] = xres[(size_t)row * D + col];
            }
        }
    }

    __syncthreads();

    for (int t = 0; t < KTILES; ++t) {
        const int cur = t & 1;
        if (t + 1 < KTILES) stage(cur ^ 1, t + 1);
        #pragma unroll
        for (int kk = 0; kk < 2; ++kk) {
            const int kc = kk * 4 + (lane >> 4);
            short8 af[2], bfr[4];
            #pragma unroll
            for (int mf = 0; mf < 2; ++mf) {
                const int ar = wid * 32 + mf * 16 + (lane & 15);
                af[mf] = *reinterpret_cast<const short8*>(
                    &As[cur][ar * 64 + ((kc ^ (ar & 7)) * 8)]);
            }
            #pragma unroll
            for (int nf = 0; nf < 4; ++nf) {
                const int br = nf * 16 + (lane & 15);
                bfr[nf] = *reinterpret_cast<const short8*>(
                    &Bs[cur][br * 64 + ((kc ^ (br & 7)) * 8)]);
            }
            #pragma unroll
            for (int mf = 0; mf < 2; ++mf)
                #pragma unroll
                for (int nf = 0; nf < 4; ++nf)
                    acc[mf][nf] = __builtin_amdgcn_mfma_f32_16x16x32_bf16(
                        af[mf], bfr[nf], acc[mf][nf], 0, 0, 0);
        }
        __syncthreads();
    }

    #pragma unroll
    for (int mf = 0; mf < 2; ++mf) {
        const int rowb = m0 + wid * 32 + mf * 16 + ((lane >> 4) << 2);
        #pragma unroll
        for (int nf = 0; nf < 4; ++nf) {
            const int col = n0 + nf * 16 + (lane & 15);
            const float bv = bias[col];
            #pragma unroll
            for (int r = 0; r < 4; ++r) {
                const int row = rowb + r;
                if (row < M)
                    Cout[(size_t)row * D + col] =
                        acc[mf][nf][r] + bv + xv[mf][nf][r];
            }
        }
    }
}

extern "C" void kernel_launch(void* const* d_in, const int* in_sizes, int n_in,
                              void* d_out, int out_size, void* d_ws, size_t ws_size,
                              hipStream_t stream) {
    const float* x      = (const float*)d_in[0];
    const int*   edge_index = (const int*)d_in[2];
    const float* rbf    = (const float*)d_in[3];
    const float* ang    = (const float*)d_in[4];
    const float* W_edge = (const float*)d_in[5];
    const float* b_edge = (const float*)d_in[6];
    const float* W1     = (const float*)d_in[7];
    const float* b1     = (const float*)d_in[8];
    const float* W2     = (const float*)d_in[9];
    const float* b2     = (const float*)d_in[10];
    float* out = (float*)d_out;

    char* w = (char*)d_ws;
    ushort* aggX = (ushort*)w;                       //  2,560,000 B [NN][128]
    ushort* W2t  = (ushort*)(w + 2560000);           //    524,288 B
    ushort* WcT  = (ushort*)(w + 3084288);           //    131,072 B [512][128]
    int*    deg  = (int*)(w + 3215360);              //     40,000 B
    float*  part = (float*)(w + 3255360);            //  1,327,104 B
    int*    ell  = (int*)(w + 4582464);              //  3,840,000 B
    ushort* h1   = (ushort*)(w + 3255360);           // 10,240,000 B (aliases part+ell)

    prep1_kernel<<<1640, 256, 0, stream>>>(W_edge, b_edge, W1, W2, part, W2t, deg);
    prep2_kernel<<<881, 256, 0, stream>>>(part, edge_index, WcT, deg, ell);
    gather_agg_kernel<<<NN / 4, 256, 0, stream>>>(deg, ell, rbf, ang, aggX);

    dim3 ggrid(D / 64, (NN + 127) / 128);   // 8 x 79 = 632 blocks, %8==0
    h1_mfma_kernel<<<ggrid, 256, 0, stream>>>(aggX, WcT, b1, h1, NN);
    mfma_gemm_kernel<<<ggrid, 256, 0, stream>>>(h1, W2t, b2, x, out, NN);
}